// Round 1
// baseline (433.274 us; speedup 1.0000x reference)
//
#include <hip/hip_runtime.h>

#define VGRID 256
#define N_TAPS 27
#define CIN 64
#define COUT 64

// Scatter point indices into the dense voxel table.
// atomicMax matches numpy's last-write-wins (arange is increasing) for
// duplicate coordinates.
__global__ void build_table_kernel(const int* __restrict__ coords,
                                   int* __restrict__ table, int n) {
    int i = blockIdx.x * blockDim.x + threadIdx.x;
    if (i >= n) return;
    int cx = coords[i * 3 + 0];
    int cy = coords[i * 3 + 1];
    int cz = coords[i * 3 + 2];
    int lin = (cx * VGRID + cy) * VGRID + cz;
    atomicMax(&table[lin], i);
}

// One wave (64 lanes) per point; lane = output channel.
__global__ void __launch_bounds__(256) conv_kernel(
        const int* __restrict__ coords, const float* __restrict__ feats,
        const float* __restrict__ weights, const int* __restrict__ table,
        float* __restrict__ out, int n) {
    int gtid = blockIdx.x * blockDim.x + threadIdx.x;
    int point = gtid >> 6;          // wave index
    int lane = threadIdx.x & 63;    // output channel
    if (point >= n) return;

    int cx = coords[point * 3 + 0];
    int cy = coords[point * 3 + 1];
    int cz = coords[point * 3 + 2];

    // Lanes 0..26 each probe one neighbor offset.
    // k = ((ox+1)*3 + (oy+1))*3 + (oz+1)  ->  ox=k/9-1, oy=(k/3)%3-1, oz=k%3-1
    int idx = -1;
    if (lane < N_TAPS) {
        int ox = lane / 9 - 1;
        int oy = (lane / 3) % 3 - 1;
        int oz = lane % 3 - 1;
        int nx = cx + ox, ny = cy + oy, nz = cz + oz;
        if (((unsigned)nx < VGRID) && ((unsigned)ny < VGRID) &&
            ((unsigned)nz < VGRID)) {
            idx = table[(nx * VGRID + ny) * VGRID + nz];
        }
    }

    unsigned long long valid = __ballot(idx >= 0);
    float acc = 0.0f;

    while (valid) {
        int k = __builtin_ctzll(valid);   // taps in ascending k order (ref order)
        valid &= valid - 1;
        int j = __shfl(idx, k);           // neighbor point index (wave-uniform)

        float f = feats[(size_t)j * CIN + lane];      // coalesced 256B load
        const float* Kk = weights + (size_t)k * CIN * COUT;
#pragma unroll
        for (int ci = 0; ci < CIN; ++ci) {
            acc = fmaf(__shfl(f, ci), Kk[ci * COUT + lane], acc);
        }
    }

    out[(size_t)point * COUT + lane] = acc;
}

extern "C" void kernel_launch(void* const* d_in, const int* in_sizes, int n_in,
                              void* d_out, int out_size, void* d_ws, size_t ws_size,
                              hipStream_t stream) {
    const int* coords = (const int*)d_in[0];
    const float* feats = (const float*)d_in[1];
    const float* weights = (const float*)d_in[2];
    float* out = (float*)d_out;

    int n = in_sizes[0] / 3;  // 262144

    // Dense voxel table: 256^3 int32 = 64 MiB in workspace.
    int* table = (int*)d_ws;
    size_t table_bytes = (size_t)VGRID * VGRID * VGRID * sizeof(int);

    // ws is re-poisoned to 0xAA before every timed launch: re-init every call.
    hipMemsetAsync(table, 0xFF, table_bytes, stream);  // all -1

    int bt_threads = 256;
    int bt_blocks = (n + bt_threads - 1) / bt_threads;
    build_table_kernel<<<bt_blocks, bt_threads, 0, stream>>>(coords, table, n);

    // One 64-lane wave per point, 4 waves per block.
    int cv_threads = 256;
    long long total_threads = (long long)n * 64;
    int cv_blocks = (int)((total_threads + cv_threads - 1) / cv_threads);
    conv_kernel<<<cv_blocks, cv_threads, 0, stream>>>(coords, feats, weights,
                                                      table, out, n);
}